// Round 5
// baseline (5557.553 us; speedup 1.0000x reference)
//
#include <hip/hip_runtime.h>
#include <hip/hip_bf16.h>
#include <stdint.h>

// LightGCN on MI355X, round 5.
// 1) CSR build: single-pass wave-ballot partition into 8 dst-bucket queues
//    (coalesced segmented writes, 8 atomics/wave), then bucket-pure count and
//    fill passes (all lanes active, 1x reads, L2-local scatter).
// 2) SpMV: z stored panel-major [4][N][16] (3.2 MB/panel fits one XCD L2);
//    blockIdx&7 keys the panel so every z-gather is XCD-L2-local. csrc is
//    streamed nt 4x (L3-served) to buy L2 residency for the gathers.

#define N_NODES 100000
#define N_EDGES 3200000
#define DIM 64

#define NBUCKET 8
#define BUCKET_NODES 12500
#define QCAP 440000            // per-bucket queue capacity (400K avg + slack)
#define BSLICE 4096
#define NBSLICE 108            // ceil(QCAP / BSLICE)

#define NPANEL 4
#define PFEAT 16               // features per panel

#define SCAN_BLOCK 256
#define SCAN_ITEMS 8
#define SCAN_CHUNK (SCAN_BLOCK * SCAN_ITEMS)  // 2048
#define SCAN_NBLOCKS ((N_NODES + SCAN_CHUNK - 1) / SCAN_CHUNK)  // 49

__device__ __forceinline__ float bl(unsigned u) { return __uint_as_float(u << 16); }
__device__ __forceinline__ float bh(unsigned u) { return __uint_as_float(u & 0xffff0000u); }

// ---- phase A: partition edges into 8 bucket queues (one thread per edge) ----
__global__ __launch_bounds__(256) void k_partition(
    const int* __restrict__ ei, int* __restrict__ qcur,
    int* __restrict__ qrow, int* __restrict__ qcol) {
    int e = blockIdx.x * 256 + threadIdx.x;
    int lane = threadIdx.x & 63;
    int r = __builtin_nontemporal_load(ei + e);
    int c = __builtin_nontemporal_load(ei + N_EDGES + e);
    int b = c / BUCKET_NODES;

#pragma unroll
    for (int bi = 0; bi < NBUCKET; bi++) {
        unsigned long long mask = __ballot(b == bi);
        if (mask == 0ull) continue;
        int leader = __ffsll((long long)mask) - 1;
        int cnt = __popcll(mask);
        int off = 0;
        if (lane == leader) off = atomicAdd(&qcur[bi], cnt);
        off = __shfl(off, leader);
        if (b == bi) {
            int pos = off + __popcll(mask & ((1ull << lane) - 1ull));
            qrow[(size_t)bi * QCAP + pos] = r;
            qcol[(size_t)bi * QCAP + pos] = c;
        }
    }
}

// ---- phase B1: bucket-pure degree count ----
__global__ __launch_bounds__(256) void k_count_b(
    const int* __restrict__ qcur, const int* __restrict__ qcol,
    int* __restrict__ deg) {
    int b = blockIdx.x & (NBUCKET - 1);
    int m = blockIdx.x >> 3;
    int cnt = qcur[b];
    int e0 = m * BSLICE;
    if (e0 >= cnt) return;
    int n = min(BSLICE, cnt - e0);
    const int* q = qcol + (size_t)b * QCAP + e0;
    for (int i = threadIdx.x; i < n; i += 256) {
        int c = __builtin_nontemporal_load(q + i);
        atomicAdd(&deg[c], 1);
    }
}

__global__ void k_dinv(const int* __restrict__ deg, float* __restrict__ dinv) {
    int i = blockIdx.x * blockDim.x + threadIdx.x;
    if (i < N_NODES) {
        int d = deg[i];
        dinv[i] = (d > 0) ? rsqrtf((float)d) : 0.0f;
    }
}

// ---- exclusive scan of deg -> base ----
__global__ void k_scan1(const int* __restrict__ deg, int* __restrict__ base,
                        int* __restrict__ bsums) {
    int t = threadIdx.x;
    int idx0 = blockIdx.x * SCAN_CHUNK + t * SCAN_ITEMS;

    int v[SCAN_ITEMS];
    int s = 0;
#pragma unroll
    for (int k = 0; k < SCAN_ITEMS; k++) {
        int idx = idx0 + k;
        v[k] = (idx < N_NODES) ? deg[idx] : 0;
        s += v[k];
    }
    int lane = t & 63;
    int waveId = t >> 6;
    int sum = s;
#pragma unroll
    for (int off = 1; off < 64; off <<= 1) {
        int u = __shfl_up(sum, off);
        if (lane >= off) sum += u;
    }
    int exclusive = sum - s;

    __shared__ int waveTotals[4];
    if (lane == 63) waveTotals[waveId] = sum;
    __syncthreads();
    int waveOff = 0;
    for (int w = 0; w < waveId; w++) waveOff += waveTotals[w];

    int run = exclusive + waveOff;
#pragma unroll
    for (int k = 0; k < SCAN_ITEMS; k++) {
        int idx = idx0 + k;
        if (idx < N_NODES) base[idx] = run;
        run += v[k];
    }
    if (t == SCAN_BLOCK - 1) bsums[blockIdx.x] = run;
}

__global__ void k_scan2(int* __restrict__ bsums, int numBlocks) {
    int lane = threadIdx.x;
    int v = (lane < numBlocks) ? bsums[lane] : 0;
    int sum = v;
#pragma unroll
    for (int off = 1; off < 64; off <<= 1) {
        int u = __shfl_up(sum, off);
        if (lane >= off) sum += u;
    }
    if (lane < numBlocks) bsums[lane] = sum - v;
}

__global__ void k_scan3(int* __restrict__ base, const int* __restrict__ bsums,
                        int* __restrict__ cursor) {
    int i = blockIdx.x * blockDim.x + threadIdx.x;
    if (i < N_NODES) {
        int b = base[i] + bsums[i / SCAN_CHUNK];
        base[i] = b;
        cursor[i] = b;
    }
}

// ---- phase B2: bucket-pure CSR fill (L2-local cursor + csrc windows) ----
__global__ __launch_bounds__(256) void k_fill_b(
    const int* __restrict__ qcur, const int* __restrict__ qrow,
    const int* __restrict__ qcol, int* __restrict__ cursor,
    int* __restrict__ csrc) {
    int b = blockIdx.x & (NBUCKET - 1);
    int m = blockIdx.x >> 3;
    int cnt = qcur[b];
    int e0 = m * BSLICE;
    if (e0 >= cnt) return;
    int n = min(BSLICE, cnt - e0);
    const int* qr = qrow + (size_t)b * QCAP + e0;
    const int* qc = qcol + (size_t)b * QCAP + e0;
    for (int i = threadIdx.x; i < n; i += 256) {
        int r = __builtin_nontemporal_load(qr + i);
        int c = __builtin_nontemporal_load(qc + i);
        int p = atomicAdd(&cursor[c], 1);
        csrc[p] = r;
    }
}

// z0 = bf16(emb * dinv), panel-major [NPANEL][N][PFEAT]. thread = 4 feats.
__global__ void k_z0(const float* __restrict__ emb, const float* __restrict__ dinv,
                     __hip_bfloat16* __restrict__ z) {
    int i = blockIdx.x * blockDim.x + threadIdx.x;
    if (i >= N_NODES * (DIM / 4)) return;
    int n = i >> 4;
    int j = i & 15;      // 4-feat group within the node
    float di = dinv[n];
    const float4 v = ((const float4*)emb)[i];
    union { ushort h[4]; uint2 u; } pk;
    __hip_bfloat16 b0 = __float2bfloat16(v.x * di);
    __hip_bfloat16 b1 = __float2bfloat16(v.y * di);
    __hip_bfloat16 b2 = __float2bfloat16(v.z * di);
    __hip_bfloat16 b3 = __float2bfloat16(v.w * di);
    pk.h[0] = *(ushort*)&b0; pk.h[1] = *(ushort*)&b1;
    pk.h[2] = *(ushort*)&b2; pk.h[3] = *(ushort*)&b3;
    int q = j >> 2;      // panel
    ((uint2*)z)[(size_t)q * N_NODES * 4 + (size_t)n * 4 + (j & 3)] = pk.u;
}

// ---- SpMV, panel-local gathers ----
// wave = one (dst node, panel). lane: el=lane&7 (2 feats), g=lane>>3 (edge slot).
// panel keyed by blockIdx&7 -> each XCD gathers only its 3.2 MB z-panel (L2-res).
// mode 0: acc = emb + xo; znext = bf16(xo*dinv)
// mode 1: acc += xo;      znext = bf16(xo*dinv)
// mode 2: acc = (acc + xo) * 0.25
__global__ __launch_bounds__(256) void k_spmv_p(
    const int* __restrict__ base, const int* __restrict__ deg,
    const int* __restrict__ csrc, const __hip_bfloat16* __restrict__ z,
    const float* __restrict__ dinv, __hip_bfloat16* __restrict__ znext,
    const float* __restrict__ emb, float* __restrict__ acc_out, int mode) {
    int low3 = blockIdx.x & 7;
    int panel = low3 >> 1;
    int dst_group = ((blockIdx.x >> 3) << 1) | (blockIdx.x & 1);
    int node = dst_group * 4 + (threadIdx.x >> 6);
    int lane = threadIdx.x & 63;
    int el = lane & 7;   // 4 B = 2 bf16 feats within panel
    int g = lane >> 3;   // edge slot 0..7

    const unsigned* zp = (const unsigned*)z + (size_t)panel * N_NODES * 8;

    int start = base[node];
    int cnt = deg[node];

    float a0 = 0.0f, a1 = 0.0f;

    int pos = 0;
    for (; pos + 32 <= cnt; pos += 32) {
        int i0 = start + pos + g;
        int s0 = __builtin_nontemporal_load(csrc + i0);
        int s1 = __builtin_nontemporal_load(csrc + i0 + 8);
        int s2 = __builtin_nontemporal_load(csrc + i0 + 16);
        int s3 = __builtin_nontemporal_load(csrc + i0 + 24);
        unsigned v0 = zp[((size_t)s0 << 3) + el];
        unsigned v1 = zp[((size_t)s1 << 3) + el];
        unsigned v2 = zp[((size_t)s2 << 3) + el];
        unsigned v3 = zp[((size_t)s3 << 3) + el];
        a0 += bl(v0); a1 += bh(v0);
        a0 += bl(v1); a1 += bh(v1);
        a0 += bl(v2); a1 += bh(v2);
        a0 += bl(v3); a1 += bh(v3);
    }
    for (; pos < cnt; pos += 8) {
        int idx = pos + g;
        if (idx < cnt) {
            int s = __builtin_nontemporal_load(csrc + start + idx);
            unsigned v = zp[((size_t)s << 3) + el];
            a0 += bl(v); a1 += bh(v);
        }
    }

    // reduce across the 8 edge slots (lane bits 3,4,5)
    a0 += __shfl_xor(a0, 8);  a1 += __shfl_xor(a1, 8);
    a0 += __shfl_xor(a0, 16); a1 += __shfl_xor(a1, 16);
    a0 += __shfl_xor(a0, 32); a1 += __shfl_xor(a1, 32);

    if (lane < 8) {  // lane == el: feats [panel*16 + el*2, +2)
        float di = dinv[node];
        float x0 = a0 * di, x1 = a1 * di;
        size_t o = (size_t)node * DIM + panel * PFEAT + el * 2;
        float2 r;
        if (mode == 0) {
            float2 e = *(const float2*)(emb + o);
            r = make_float2(e.x + x0, e.y + x1);
        } else if (mode == 1) {
            float2 p = *(const float2*)(acc_out + o);
            r = make_float2(p.x + x0, p.y + x1);
        } else {
            float2 p = *(const float2*)(acc_out + o);
            r = make_float2((p.x + x0) * 0.25f, (p.y + x1) * 0.25f);
        }
        *(float2*)(acc_out + o) = r;

        if (mode != 2) {
            __hip_bfloat16 c0 = __float2bfloat16(x0 * di);
            __hip_bfloat16 c1 = __float2bfloat16(x1 * di);
            unsigned u = (unsigned)*(ushort*)&c0 | ((unsigned)*(ushort*)&c1 << 16);
            ((unsigned*)znext)[((size_t)panel * N_NODES + node) * 8 + el] = u;
        }
    }
}

extern "C" void kernel_launch(void* const* d_in, const int* in_sizes, int n_in,
                              void* d_out, int out_size, void* d_ws, size_t ws_size,
                              hipStream_t stream) {
    const float* emb = (const float*)d_in[0];
    const int* ei = (const int*)d_in[1];  // [2, E]: row = ei[0:E], col = ei[E:2E]
    float* out = (float*)d_out;

    char* ws = (char*)d_ws;
    size_t off = 0;
    auto alloc = [&](size_t bytes) -> void* {
        void* p = ws + off;
        off += (bytes + 511) & ~(size_t)511;
        return p;
    };
    int* deg = (int*)alloc((size_t)N_NODES * 4);
    float* dinv = (float*)alloc((size_t)N_NODES * 4);
    int* base = (int*)alloc((size_t)N_NODES * 4);
    int* cursor = (int*)alloc((size_t)N_NODES * 4);
    int* bsums = (int*)alloc(64 * 4);
    int* qcur = (int*)alloc(NBUCKET * 4);
    int* csrc = (int*)alloc((size_t)N_EDGES * 4);
    // bucket queues; z buffers reuse this region AFTER fill is done (stream-ordered)
    int* qrow = (int*)alloc((size_t)NBUCKET * QCAP * 4);   // 14.1 MB
    int* qcol = (int*)alloc((size_t)NBUCKET * QCAP * 4);   // 14.1 MB
    __hip_bfloat16* zA = (__hip_bfloat16*)qrow;            // 12.8 MB, aliases qrow
    __hip_bfloat16* zB = (__hip_bfloat16*)qcol;            // 12.8 MB, aliases qcol

    hipMemsetAsync(deg, 0, (size_t)N_NODES * 4, stream);
    hipMemsetAsync(qcur, 0, NBUCKET * 4, stream);

    int nBlocks = (N_NODES + 255) / 256;

    k_partition<<<N_EDGES / 256, 256, 0, stream>>>(ei, qcur, qrow, qcol);
    k_count_b<<<NBUCKET * NBSLICE, 256, 0, stream>>>(qcur, qcol, deg);
    k_dinv<<<nBlocks, 256, 0, stream>>>(deg, dinv);
    k_scan1<<<SCAN_NBLOCKS, SCAN_BLOCK, 0, stream>>>(deg, base, bsums);
    k_scan2<<<1, 64, 0, stream>>>(bsums, SCAN_NBLOCKS);
    k_scan3<<<nBlocks, 256, 0, stream>>>(base, bsums, cursor);
    k_fill_b<<<NBUCKET * NBSLICE, 256, 0, stream>>>(qcur, qrow, qcol, cursor, csrc);
    // fill consumed qrow/qcol; zA/zB now own that storage (same stream => ordered)
    k_z0<<<(N_NODES * (DIM / 4) + 255) / 256, 256, 0, stream>>>(emb, dinv, zA);

    int spmvBlocks = NBUCKET * (N_NODES / 8);  // 100000: (panel,parity) x 12500 chunks
    k_spmv_p<<<spmvBlocks, 256, 0, stream>>>(base, deg, csrc, zA, dinv, zB, emb, out, 0);
    k_spmv_p<<<spmvBlocks, 256, 0, stream>>>(base, deg, csrc, zB, dinv, zA, emb, out, 1);
    k_spmv_p<<<spmvBlocks, 256, 0, stream>>>(base, deg, csrc, zA, dinv, zB, emb, out, 2);
}

// Round 7
// 1040.264 us; speedup vs baseline: 5.3424x; 5.3424x over previous
//
#include <hip/hip_runtime.h>
#include <hip/hip_bf16.h>
#include <stdint.h>

// LightGCN on MI355X, round 7 (R6 design, compile fix: nontemporal_store needs
// ext_vector_type pointers, not HIP_vector_type float4/uint4).
//  - k_part: 16384 edges/block, private-slot LDS histogram + per-bucket block
//    scan, ONE padded global atomic per bucket per block (1568 total).
//  - SpMV v2: panel-major z [4][N][16] (3.2 MB/panel, XCD-L2-resident via
//    blockIdx&7 keying), 16 B gathers / 32 edges per load inst, nt csrc
//    stream, nt stores.

#define N_NODES 100000
#define N_EDGES 3200000
#define DIM 64

#define NBUCKET 8
#define BUCKET_NODES 12500
#define QCAP 440000
#define QPAD 32                // qcur padding: one counter per 128 B
#define CHUNK 16384
#define NBLK ((N_EDGES + CHUNK - 1) / CHUNK)  // 196
#define BSLICE 4096
#define NBSLICE 108            // ceil(QCAP / BSLICE)

#define SCAN_BLOCK 256
#define SCAN_ITEMS 8
#define SCAN_CHUNK (SCAN_BLOCK * SCAN_ITEMS)  // 2048
#define SCAN_NBLOCKS ((N_NODES + SCAN_CHUNK - 1) / SCAN_CHUNK)  // 49

typedef float v4f __attribute__((ext_vector_type(4)));
typedef unsigned v4u __attribute__((ext_vector_type(4)));

__device__ __forceinline__ float bl(unsigned u) { return __uint_as_float(u << 16); }
__device__ __forceinline__ float bh(unsigned u) { return __uint_as_float(u & 0xffff0000u); }

// ---- partition: 8 dst-bucket queues, block-aggregated reservation ----
__global__ __launch_bounds__(256) void k_part(
    const int* __restrict__ ei, int* __restrict__ qcur,
    int* __restrict__ qrow, int* __restrict__ qcol) {
    __shared__ int scn[8 * 257];
    __shared__ int totArr[8];
    __shared__ int gbase[8];
    int t = threadIdx.x;
    int c0 = blockIdx.x * CHUNK;
    int nEdge = min(CHUNK, N_EDGES - c0);
    const int* col = ei + N_EDGES + c0;
    const int* row = ei + c0;

    for (int i = t; i < 8 * 257; i += 256) scn[i] = 0;
    __syncthreads();

    // pass 1: private-slot histogram (column t is exclusively thread t's)
    for (int k = 0; k < CHUNK / 256; k++) {
        int idx = t + k * 256;
        if (idx < nEdge) {
            int b = col[idx] / BUCKET_NODES;
            scn[b * 257 + t] += 1;
        }
    }
    __syncthreads();

    // per-bucket exclusive scan over the 256 thread-columns (wave w: buckets 2w,2w+1)
    int lane = t & 63;
    int w = t >> 6;
    for (int b = 2 * w; b < 2 * w + 2; b++) {
        int carry = 0;
        for (int k = 0; k < 4; k++) {
            int v = scn[b * 257 + k * 64 + lane];
            int incl = v;
#pragma unroll
            for (int off = 1; off < 64; off <<= 1) {
                int u = __shfl_up(incl, off);
                if (lane >= off) incl += u;
            }
            scn[b * 257 + k * 64 + lane] = carry + incl - v;
            carry += __shfl(incl, 63);
        }
        if (lane == 0) totArr[b] = carry;
    }
    __syncthreads();
    if (t < 8) gbase[t] = atomicAdd(&qcur[t * QPAD], totArr[t]);
    __syncthreads();
#pragma unroll
    for (int b = 0; b < 8; b++) scn[b * 257 + t] += gbase[b];
    // no sync needed: slots are thread-private from here

    // pass 2: place edges
    for (int k = 0; k < CHUNK / 256; k++) {
        int idx = t + k * 256;
        if (idx < nEdge) {
            int c = col[idx];
            int r = row[idx];
            int b = c / BUCKET_NODES;
            int a = b * 257 + t;
            int p = scn[a];
            scn[a] = p + 1;
            qrow[(size_t)b * QCAP + p] = r;
            qcol[(size_t)b * QCAP + p] = c;
        }
    }
}

// ---- bucket-pure degree count ----
__global__ __launch_bounds__(256) void k_count_b(
    const int* __restrict__ qcur, const int* __restrict__ qcol,
    int* __restrict__ deg) {
    int b = blockIdx.x & (NBUCKET - 1);
    int m = blockIdx.x >> 3;
    int cnt = qcur[b * QPAD];
    int e0 = m * BSLICE;
    if (e0 >= cnt) return;
    int n = min(BSLICE, cnt - e0);
    const int* q = qcol + (size_t)b * QCAP + e0;
    for (int i = threadIdx.x; i < n; i += 256) {
        atomicAdd(&deg[q[i]], 1);
    }
}

__global__ void k_dinv(const int* __restrict__ deg, float* __restrict__ dinv) {
    int i = blockIdx.x * blockDim.x + threadIdx.x;
    if (i < N_NODES) {
        int d = deg[i];
        dinv[i] = (d > 0) ? rsqrtf((float)d) : 0.0f;
    }
}

// ---- exclusive scan of deg -> base ----
__global__ void k_scan1(const int* __restrict__ deg, int* __restrict__ base,
                        int* __restrict__ bsums) {
    int t = threadIdx.x;
    int idx0 = blockIdx.x * SCAN_CHUNK + t * SCAN_ITEMS;

    int v[SCAN_ITEMS];
    int s = 0;
#pragma unroll
    for (int k = 0; k < SCAN_ITEMS; k++) {
        int idx = idx0 + k;
        v[k] = (idx < N_NODES) ? deg[idx] : 0;
        s += v[k];
    }
    int lane = t & 63;
    int waveId = t >> 6;
    int sum = s;
#pragma unroll
    for (int off = 1; off < 64; off <<= 1) {
        int u = __shfl_up(sum, off);
        if (lane >= off) sum += u;
    }
    int exclusive = sum - s;

    __shared__ int waveTotals[4];
    if (lane == 63) waveTotals[waveId] = sum;
    __syncthreads();
    int waveOff = 0;
    for (int w = 0; w < waveId; w++) waveOff += waveTotals[w];

    int run = exclusive + waveOff;
#pragma unroll
    for (int k = 0; k < SCAN_ITEMS; k++) {
        int idx = idx0 + k;
        if (idx < N_NODES) base[idx] = run;
        run += v[k];
    }
    if (t == SCAN_BLOCK - 1) bsums[blockIdx.x] = run;
}

__global__ void k_scan2(int* __restrict__ bsums, int numBlocks) {
    int lane = threadIdx.x;
    int v = (lane < numBlocks) ? bsums[lane] : 0;
    int sum = v;
#pragma unroll
    for (int off = 1; off < 64; off <<= 1) {
        int u = __shfl_up(sum, off);
        if (lane >= off) sum += u;
    }
    if (lane < numBlocks) bsums[lane] = sum - v;
}

__global__ void k_scan3(int* __restrict__ base, const int* __restrict__ bsums,
                        int* __restrict__ cursor) {
    int i = blockIdx.x * blockDim.x + threadIdx.x;
    if (i < N_NODES) {
        int b = base[i] + bsums[i / SCAN_CHUNK];
        base[i] = b;
        cursor[i] = b;
    }
}

// ---- bucket-pure CSR fill (cursor + csrc windows stay XCD-L2-local) ----
__global__ __launch_bounds__(256) void k_fill_b(
    const int* __restrict__ qcur, const int* __restrict__ qrow,
    const int* __restrict__ qcol, int* __restrict__ cursor,
    int* __restrict__ csrc) {
    int b = blockIdx.x & (NBUCKET - 1);
    int m = blockIdx.x >> 3;
    int cnt = qcur[b * QPAD];
    int e0 = m * BSLICE;
    if (e0 >= cnt) return;
    int n = min(BSLICE, cnt - e0);
    const int* qr = qrow + (size_t)b * QCAP + e0;
    const int* qc = qcol + (size_t)b * QCAP + e0;
    for (int i = threadIdx.x; i < n; i += 256) {
        int r = qr[i];
        int c = qc[i];
        int p = atomicAdd(&cursor[c], 1);
        csrc[p] = r;
    }
}

// z0 = bf16(emb * dinv), panel-major [4][N][16].
__global__ void k_z0(const float* __restrict__ emb, const float* __restrict__ dinv,
                     __hip_bfloat16* __restrict__ z) {
    int i = blockIdx.x * blockDim.x + threadIdx.x;
    if (i >= N_NODES * (DIM / 4)) return;
    int n = i >> 4;
    int j = i & 15;
    float di = dinv[n];
    const float4 v = ((const float4*)emb)[i];
    union { ushort h[4]; uint2 u; } pk;
    __hip_bfloat16 b0 = __float2bfloat16(v.x * di);
    __hip_bfloat16 b1 = __float2bfloat16(v.y * di);
    __hip_bfloat16 b2 = __float2bfloat16(v.z * di);
    __hip_bfloat16 b3 = __float2bfloat16(v.w * di);
    pk.h[0] = *(ushort*)&b0; pk.h[1] = *(ushort*)&b1;
    pk.h[2] = *(ushort*)&b2; pk.h[3] = *(ushort*)&b3;
    int q = j >> 2;
    ((uint2*)z)[(size_t)q * N_NODES * 4 + (size_t)n * 4 + (j & 3)] = pk.u;
}

// ---- SpMV v2: panel-local gathers, 16 B / lane, 32 edges per load inst ----
// wave = (node, panel). el=lane&1 (16 B half of 32 B panel row), g=lane>>1.
// mode 0: acc = emb + xo; znext = bf16(xo*dinv)
// mode 1: acc += xo;      znext = bf16(xo*dinv)
// mode 2: acc = (acc + xo) * 0.25
__global__ __launch_bounds__(256) void k_spmv2(
    const int* __restrict__ base, const int* __restrict__ deg,
    const int* __restrict__ csrc, const __hip_bfloat16* __restrict__ z,
    const float* __restrict__ dinv, __hip_bfloat16* __restrict__ znext,
    const float* __restrict__ emb, float* __restrict__ acc_out, int mode) {
    int bid = blockIdx.x;
    int panel = (bid & 7) >> 1;
    int grp = ((bid >> 3) << 1) | (bid & 1);        // 0..24999
    int node = grp * 4 + (threadIdx.x >> 6);
    int lane = threadIdx.x & 63;
    int g = lane >> 1;   // edge slot 0..31
    int el = lane & 1;   // which 16 B of the 32 B panel row

    const v4u* zp = (const v4u*)(z + (size_t)panel * N_NODES * 16);

    int start = base[node];
    int cnt = deg[node];

    float a[8] = {0, 0, 0, 0, 0, 0, 0, 0};

#define ACCUM(V)                                 \
    do {                                         \
        a[0] += bl((V).x); a[1] += bh((V).x);    \
        a[2] += bl((V).y); a[3] += bh((V).y);    \
        a[4] += bl((V).z); a[5] += bh((V).z);    \
        a[6] += bl((V).w); a[7] += bh((V).w);    \
    } while (0)

    int pos = 0;
    for (; pos + 32 <= cnt; pos += 32) {
        int s = __builtin_nontemporal_load(csrc + start + pos + g);
        v4u v = zp[(size_t)s * 2 + el];
        ACCUM(v);
    }
    if (pos < cnt) {
        int idx = pos + g;
        if (idx < cnt) {
            int s = __builtin_nontemporal_load(csrc + start + idx);
            v4u v = zp[(size_t)s * 2 + el];
            ACCUM(v);
        }
    }
#undef ACCUM

    // reduce over edge slots (lane bits 1..5)
#pragma unroll
    for (int j = 0; j < 8; j++) {
        a[j] += __shfl_xor(a[j], 2);
        a[j] += __shfl_xor(a[j], 4);
        a[j] += __shfl_xor(a[j], 8);
        a[j] += __shfl_xor(a[j], 16);
        a[j] += __shfl_xor(a[j], 32);
    }

    if (lane < 2) {  // lane == el: feats [panel*16 + el*8, +8)
        float di = dinv[node];
        size_t o = (size_t)node * DIM + panel * 16 + el * 8;
        float xo[8];
#pragma unroll
        for (int j = 0; j < 8; j++) xo[j] = a[j] * di;

        v4f o0, o1;
        if (mode == 0) {
            const v4f e0 = ((const v4f*)(emb + o))[0];
            const v4f e1 = ((const v4f*)(emb + o))[1];
            o0 = (v4f){e0.x + xo[0], e0.y + xo[1], e0.z + xo[2], e0.w + xo[3]};
            o1 = (v4f){e1.x + xo[4], e1.y + xo[5], e1.z + xo[6], e1.w + xo[7]};
        } else if (mode == 1) {
            const v4f a0 = ((const v4f*)(acc_out + o))[0];
            const v4f a1 = ((const v4f*)(acc_out + o))[1];
            o0 = (v4f){a0.x + xo[0], a0.y + xo[1], a0.z + xo[2], a0.w + xo[3]};
            o1 = (v4f){a1.x + xo[4], a1.y + xo[5], a1.z + xo[6], a1.w + xo[7]};
        } else {
            const v4f a0 = ((const v4f*)(acc_out + o))[0];
            const v4f a1 = ((const v4f*)(acc_out + o))[1];
            o0 = (v4f){(a0.x + xo[0]) * 0.25f, (a0.y + xo[1]) * 0.25f,
                       (a0.z + xo[2]) * 0.25f, (a0.w + xo[3]) * 0.25f};
            o1 = (v4f){(a1.x + xo[4]) * 0.25f, (a1.y + xo[5]) * 0.25f,
                       (a1.z + xo[6]) * 0.25f, (a1.w + xo[7]) * 0.25f};
        }
        __builtin_nontemporal_store(o0, (v4f*)(acc_out + o));
        __builtin_nontemporal_store(o1, (v4f*)(acc_out + o) + 1);

        if (mode != 2) {
            union { ushort h[8]; v4u u; } pk;
#pragma unroll
            for (int j = 0; j < 8; j++) {
                __hip_bfloat16 b = __float2bfloat16(xo[j] * di);
                pk.h[j] = *(ushort*)&b;
            }
            v4u* zn = (v4u*)(znext + (size_t)panel * N_NODES * 16 + (size_t)node * 16) + el;
            __builtin_nontemporal_store(pk.u, zn);
        }
    }
}

extern "C" void kernel_launch(void* const* d_in, const int* in_sizes, int n_in,
                              void* d_out, int out_size, void* d_ws, size_t ws_size,
                              hipStream_t stream) {
    const float* emb = (const float*)d_in[0];
    const int* ei = (const int*)d_in[1];  // [2, E]: row = ei[0:E], col = ei[E:2E]
    float* out = (float*)d_out;

    char* ws = (char*)d_ws;
    size_t off = 0;
    auto alloc = [&](size_t bytes) -> void* {
        void* p = ws + off;
        off += (bytes + 511) & ~(size_t)511;
        return p;
    };
    int* deg = (int*)alloc((size_t)N_NODES * 4);
    float* dinv = (float*)alloc((size_t)N_NODES * 4);
    int* base = (int*)alloc((size_t)N_NODES * 4);
    int* cursor = (int*)alloc((size_t)N_NODES * 4);
    int* bsums = (int*)alloc(64 * 4);
    int* qcur = (int*)alloc(NBUCKET * QPAD * 4);
    int* csrc = (int*)alloc((size_t)N_EDGES * 4);
    int* qrow = (int*)alloc((size_t)NBUCKET * QCAP * 4);   // 14.1 MB
    int* qcol = (int*)alloc((size_t)NBUCKET * QCAP * 4);   // 14.1 MB
    __hip_bfloat16* zA = (__hip_bfloat16*)qrow;            // 12.8 MB, aliases qrow (after fill)
    __hip_bfloat16* zB = (__hip_bfloat16*)qcol;            // 12.8 MB, aliases qcol (after fill)

    (void)hipMemsetAsync(deg, 0, (size_t)N_NODES * 4, stream);
    (void)hipMemsetAsync(qcur, 0, NBUCKET * QPAD * 4, stream);

    int nBlocks = (N_NODES + 255) / 256;

    k_part<<<NBLK, 256, 0, stream>>>(ei, qcur, qrow, qcol);
    k_count_b<<<NBUCKET * NBSLICE, 256, 0, stream>>>(qcur, qcol, deg);
    k_dinv<<<nBlocks, 256, 0, stream>>>(deg, dinv);
    k_scan1<<<SCAN_NBLOCKS, SCAN_BLOCK, 0, stream>>>(deg, base, bsums);
    k_scan2<<<1, 64, 0, stream>>>(bsums, SCAN_NBLOCKS);
    k_scan3<<<nBlocks, 256, 0, stream>>>(base, bsums, cursor);
    k_fill_b<<<NBUCKET * NBSLICE, 256, 0, stream>>>(qcur, qrow, qcol, cursor, csrc);
    // queues consumed; zA/zB own that storage now (same stream => ordered)
    k_z0<<<(N_NODES * (DIM / 4) + 255) / 256, 256, 0, stream>>>(emb, dinv, zA);

    int spmvBlocks = N_NODES;  // (node/4, panel, parity) decode; 4 waves/block
    k_spmv2<<<spmvBlocks, 256, 0, stream>>>(base, deg, csrc, zA, dinv, zB, emb, out, 0);
    k_spmv2<<<spmvBlocks, 256, 0, stream>>>(base, deg, csrc, zB, dinv, zA, emb, out, 1);
    k_spmv2<<<spmvBlocks, 256, 0, stream>>>(base, deg, csrc, zA, dinv, zB, emb, out, 2);
}

// Round 8
// 960.211 us; speedup vs baseline: 5.7878x; 1.0834x over previous
//
#include <hip/hip_runtime.h>
#include <hip/hip_bf16.h>
#include <stdint.h>

// LightGCN on MI355X, round 8.
// - SpMV p3: panel-major z [4][N][16] (3.2 MB/panel, XCD-keyed via blockIdx&7);
//   compacted butterfly reduction (18 insts vs 80); ALL streaming accesses nt
//   (csrc, emb/acc reads, acc/znext writes) so only the z-panel lives in L2.
// - Build: deg count fused into k_part pass 1 (k_count_b dropped).

#define N_NODES 100000
#define N_EDGES 3200000
#define DIM 64

#define NBUCKET 8
#define BUCKET_NODES 12500
#define QCAP 440000
#define QPAD 32                // qcur padding: one counter per 128 B
#define CHUNK 16384
#define NBLK ((N_EDGES + CHUNK - 1) / CHUNK)  // 196
#define BSLICE 4096
#define NBSLICE 108            // ceil(QCAP / BSLICE)

#define SCAN_BLOCK 256
#define SCAN_ITEMS 8
#define SCAN_CHUNK (SCAN_BLOCK * SCAN_ITEMS)  // 2048
#define SCAN_NBLOCKS ((N_NODES + SCAN_CHUNK - 1) / SCAN_CHUNK)  // 49

typedef float v4f __attribute__((ext_vector_type(4)));
typedef unsigned v4u __attribute__((ext_vector_type(4)));

__device__ __forceinline__ float bl(unsigned u) { return __uint_as_float(u << 16); }
__device__ __forceinline__ float bh(unsigned u) { return __uint_as_float(u & 0xffff0000u); }

// ---- partition into 8 dst-bucket queues + fused degree count ----
__global__ __launch_bounds__(256) void k_part(
    const int* __restrict__ ei, int* __restrict__ qcur,
    int* __restrict__ qrow, int* __restrict__ qcol, int* __restrict__ deg) {
    __shared__ int scn[8 * 257];
    __shared__ int totArr[8];
    __shared__ int gbase[8];
    int t = threadIdx.x;
    int c0 = blockIdx.x * CHUNK;
    int nEdge = min(CHUNK, N_EDGES - c0);
    const int* col = ei + N_EDGES + c0;
    const int* row = ei + c0;

    for (int i = t; i < 8 * 257; i += 256) scn[i] = 0;
    __syncthreads();

    // pass 1: private-slot histogram + fused global degree count
    for (int k = 0; k < CHUNK / 256; k++) {
        int idx = t + k * 256;
        if (idx < nEdge) {
            int c = col[idx];
            scn[(c / BUCKET_NODES) * 257 + t] += 1;
            atomicAdd(&deg[c], 1);
        }
    }
    __syncthreads();

    // per-bucket exclusive scan over 256 thread-columns (wave w: buckets 2w,2w+1)
    int lane = t & 63;
    int w = t >> 6;
    for (int b = 2 * w; b < 2 * w + 2; b++) {
        int carry = 0;
        for (int k = 0; k < 4; k++) {
            int v = scn[b * 257 + k * 64 + lane];
            int incl = v;
#pragma unroll
            for (int off = 1; off < 64; off <<= 1) {
                int u = __shfl_up(incl, off);
                if (lane >= off) incl += u;
            }
            scn[b * 257 + k * 64 + lane] = carry + incl - v;
            carry += __shfl(incl, 63);
        }
        if (lane == 0) totArr[b] = carry;
    }
    __syncthreads();
    if (t < 8) gbase[t] = atomicAdd(&qcur[t * QPAD], totArr[t]);
    __syncthreads();
#pragma unroll
    for (int b = 0; b < 8; b++) scn[b * 257 + t] += gbase[b];

    // pass 2: place edges
    for (int k = 0; k < CHUNK / 256; k++) {
        int idx = t + k * 256;
        if (idx < nEdge) {
            int c = col[idx];
            int r = row[idx];
            int b = c / BUCKET_NODES;
            int a = b * 257 + t;
            int p = scn[a];
            scn[a] = p + 1;
            qrow[(size_t)b * QCAP + p] = r;
            qcol[(size_t)b * QCAP + p] = c;
        }
    }
}

__global__ void k_dinv(const int* __restrict__ deg, float* __restrict__ dinv) {
    int i = blockIdx.x * blockDim.x + threadIdx.x;
    if (i < N_NODES) {
        int d = deg[i];
        dinv[i] = (d > 0) ? rsqrtf((float)d) : 0.0f;
    }
}

// ---- exclusive scan of deg -> base ----
__global__ void k_scan1(const int* __restrict__ deg, int* __restrict__ base,
                        int* __restrict__ bsums) {
    int t = threadIdx.x;
    int idx0 = blockIdx.x * SCAN_CHUNK + t * SCAN_ITEMS;

    int v[SCAN_ITEMS];
    int s = 0;
#pragma unroll
    for (int k = 0; k < SCAN_ITEMS; k++) {
        int idx = idx0 + k;
        v[k] = (idx < N_NODES) ? deg[idx] : 0;
        s += v[k];
    }
    int lane = t & 63;
    int waveId = t >> 6;
    int sum = s;
#pragma unroll
    for (int off = 1; off < 64; off <<= 1) {
        int u = __shfl_up(sum, off);
        if (lane >= off) sum += u;
    }
    int exclusive = sum - s;

    __shared__ int waveTotals[4];
    if (lane == 63) waveTotals[waveId] = sum;
    __syncthreads();
    int waveOff = 0;
    for (int w = 0; w < waveId; w++) waveOff += waveTotals[w];

    int run = exclusive + waveOff;
#pragma unroll
    for (int k = 0; k < SCAN_ITEMS; k++) {
        int idx = idx0 + k;
        if (idx < N_NODES) base[idx] = run;
        run += v[k];
    }
    if (t == SCAN_BLOCK - 1) bsums[blockIdx.x] = run;
}

__global__ void k_scan2(int* __restrict__ bsums, int numBlocks) {
    int lane = threadIdx.x;
    int v = (lane < numBlocks) ? bsums[lane] : 0;
    int sum = v;
#pragma unroll
    for (int off = 1; off < 64; off <<= 1) {
        int u = __shfl_up(sum, off);
        if (lane >= off) sum += u;
    }
    if (lane < numBlocks) bsums[lane] = sum - v;
}

__global__ void k_scan3(int* __restrict__ base, const int* __restrict__ bsums,
                        int* __restrict__ cursor) {
    int i = blockIdx.x * blockDim.x + threadIdx.x;
    if (i < N_NODES) {
        int b = base[i] + bsums[i / SCAN_CHUNK];
        base[i] = b;
        cursor[i] = b;
    }
}

// ---- bucket-pure CSR fill (cursor + csrc windows stay XCD-L2-local) ----
__global__ __launch_bounds__(256) void k_fill_b(
    const int* __restrict__ qcur, const int* __restrict__ qrow,
    const int* __restrict__ qcol, int* __restrict__ cursor,
    int* __restrict__ csrc) {
    int b = blockIdx.x & (NBUCKET - 1);
    int m = blockIdx.x >> 3;
    int cnt = qcur[b * QPAD];
    int e0 = m * BSLICE;
    if (e0 >= cnt) return;
    int n = min(BSLICE, cnt - e0);
    const int* qr = qrow + (size_t)b * QCAP + e0;
    const int* qc = qcol + (size_t)b * QCAP + e0;
    for (int i = threadIdx.x; i < n; i += 256) {
        int r = qr[i];
        int c = qc[i];
        int p = atomicAdd(&cursor[c], 1);
        csrc[p] = r;
    }
}

// z0 = bf16(emb * dinv), panel-major [4][N][16].
__global__ void k_z0(const float* __restrict__ emb, const float* __restrict__ dinv,
                     __hip_bfloat16* __restrict__ z) {
    int i = blockIdx.x * blockDim.x + threadIdx.x;
    if (i >= N_NODES * (DIM / 4)) return;
    int n = i >> 4;
    int j = i & 15;
    float di = dinv[n];
    const float4 v = ((const float4*)emb)[i];
    union { ushort h[4]; uint2 u; } pk;
    __hip_bfloat16 b0 = __float2bfloat16(v.x * di);
    __hip_bfloat16 b1 = __float2bfloat16(v.y * di);
    __hip_bfloat16 b2 = __float2bfloat16(v.z * di);
    __hip_bfloat16 b3 = __float2bfloat16(v.w * di);
    pk.h[0] = *(ushort*)&b0; pk.h[1] = *(ushort*)&b1;
    pk.h[2] = *(ushort*)&b2; pk.h[3] = *(ushort*)&b3;
    int q = j >> 2;
    ((uint2*)z)[(size_t)q * N_NODES * 4 + (size_t)n * 4 + (j & 3)] = pk.u;
}

// ---- SpMV p3: panel-local gathers + compacted butterfly reduction ----
// wave = (node, panel). g=lane>>1 edge slot (0..31), el=lane&1 (16 B half).
// After reduction lane<16 holds feat f = el*8 + (g&1)*4 + ((g>>1)&1)*2 + (g>>2).
__global__ __launch_bounds__(256) void k_spmv3(
    const int* __restrict__ base, const int* __restrict__ deg,
    const int* __restrict__ csrc, const __hip_bfloat16* __restrict__ z,
    const float* __restrict__ dinv, __hip_bfloat16* __restrict__ znext,
    const float* __restrict__ emb, float* __restrict__ acc_out, int mode) {
    int bid = blockIdx.x;
    int panel = (bid & 7) >> 1;
    int grp = ((bid >> 3) << 1) | (bid & 1);        // 0..24999
    int node = grp * 4 + (threadIdx.x >> 6);
    int lane = threadIdx.x & 63;
    int g = lane >> 1;
    int el = lane & 1;

    const v4u* zp = (const v4u*)(z + (size_t)panel * N_NODES * 16);

    int start = base[node];
    int cnt = deg[node];

    float a[8] = {0, 0, 0, 0, 0, 0, 0, 0};

#define ACCUM(V)                                 \
    do {                                         \
        a[0] += bl((V).x); a[1] += bh((V).x);    \
        a[2] += bl((V).y); a[3] += bh((V).y);    \
        a[4] += bl((V).z); a[5] += bh((V).z);    \
        a[6] += bl((V).w); a[7] += bh((V).w);    \
    } while (0)

    int pos = 0;
    for (; pos + 32 <= cnt; pos += 32) {
        int s = __builtin_nontemporal_load(csrc + start + pos + g);
        v4u v = zp[(size_t)s * 2 + el];
        ACCUM(v);
    }
    if (pos < cnt) {
        int idx = pos + g;
        if (idx < cnt) {
            int s = __builtin_nontemporal_load(csrc + start + idx);
            v4u v = zp[(size_t)s * 2 + el];
            ACCUM(v);
        }
    }
#undef ACCUM

    // compacted butterfly: halve accs while reducing lanes (18 insts total)
    {
        int selb = g & 1;  // xor 2
#pragma unroll
        for (int j = 0; j < 4; j++) {
            float snd = selb ? a[j] : a[j + 4];
            float kp  = selb ? a[j + 4] : a[j];
            a[j] = kp + __shfl_xor(snd, 2);
        }
        selb = (g >> 1) & 1;  // xor 4
#pragma unroll
        for (int j = 0; j < 2; j++) {
            float snd = selb ? a[j] : a[j + 2];
            float kp  = selb ? a[j + 2] : a[j];
            a[j] = kp + __shfl_xor(snd, 4);
        }
        selb = (g >> 2) & 1;  // xor 8
        {
            float snd = selb ? a[0] : a[1];
            float kp  = selb ? a[1] : a[0];
            a[0] = kp + __shfl_xor(snd, 8);
        }
        a[0] += __shfl_xor(a[0], 16);
        a[0] += __shfl_xor(a[0], 32);
    }

    if (lane < 16) {
        int f = el * 8 + ((g & 1) << 2) + (((g >> 1) & 1) << 1) + (g >> 2);
        float di = dinv[node];
        float xo = a[0] * di;
        size_t o = (size_t)node * DIM + panel * 16 + f;
        float outv;
        if (mode == 0) {
            outv = __builtin_nontemporal_load(emb + o) + xo;
        } else if (mode == 1) {
            outv = __builtin_nontemporal_load(acc_out + o) + xo;
        } else {
            outv = (__builtin_nontemporal_load(acc_out + o) + xo) * 0.25f;
        }
        __builtin_nontemporal_store(outv, acc_out + o);

        if (mode != 2) {
            __hip_bfloat16 b = __float2bfloat16(xo * di);
            ushort* zn = (ushort*)znext + (size_t)panel * N_NODES * 16 +
                         (size_t)node * 16 + f;
            __builtin_nontemporal_store(*(ushort*)&b, zn);
        }
    }
}

extern "C" void kernel_launch(void* const* d_in, const int* in_sizes, int n_in,
                              void* d_out, int out_size, void* d_ws, size_t ws_size,
                              hipStream_t stream) {
    const float* emb = (const float*)d_in[0];
    const int* ei = (const int*)d_in[1];  // [2, E]: row = ei[0:E], col = ei[E:2E]
    float* out = (float*)d_out;

    char* ws = (char*)d_ws;
    size_t off = 0;
    auto alloc = [&](size_t bytes) -> void* {
        void* p = ws + off;
        off += (bytes + 511) & ~(size_t)511;
        return p;
    };
    int* deg = (int*)alloc((size_t)N_NODES * 4);
    float* dinv = (float*)alloc((size_t)N_NODES * 4);
    int* base = (int*)alloc((size_t)N_NODES * 4);
    int* cursor = (int*)alloc((size_t)N_NODES * 4);
    int* bsums = (int*)alloc(64 * 4);
    int* qcur = (int*)alloc(NBUCKET * QPAD * 4);
    int* csrc = (int*)alloc((size_t)N_EDGES * 4);
    int* qrow = (int*)alloc((size_t)NBUCKET * QCAP * 4);   // 14.1 MB
    int* qcol = (int*)alloc((size_t)NBUCKET * QCAP * 4);   // 14.1 MB
    __hip_bfloat16* zA = (__hip_bfloat16*)qrow;            // aliases qrow (after fill)
    __hip_bfloat16* zB = (__hip_bfloat16*)qcol;            // aliases qcol (after fill)

    (void)hipMemsetAsync(deg, 0, (size_t)N_NODES * 4, stream);
    (void)hipMemsetAsync(qcur, 0, NBUCKET * QPAD * 4, stream);

    int nBlocks = (N_NODES + 255) / 256;

    k_part<<<NBLK, 256, 0, stream>>>(ei, qcur, qrow, qcol, deg);
    k_dinv<<<nBlocks, 256, 0, stream>>>(deg, dinv);
    k_scan1<<<SCAN_NBLOCKS, SCAN_BLOCK, 0, stream>>>(deg, base, bsums);
    k_scan2<<<1, 64, 0, stream>>>(bsums, SCAN_NBLOCKS);
    k_scan3<<<nBlocks, 256, 0, stream>>>(base, bsums, cursor);
    k_fill_b<<<NBUCKET * NBSLICE, 256, 0, stream>>>(qcur, qrow, qcol, cursor, csrc);
    // queues consumed; zA/zB own that storage now (same stream => ordered)
    k_z0<<<(N_NODES * (DIM / 4) + 255) / 256, 256, 0, stream>>>(emb, dinv, zA);

    int spmvBlocks = N_NODES;  // (node-group, panel, parity) decode; 4 waves/block
    k_spmv3<<<spmvBlocks, 256, 0, stream>>>(base, deg, csrc, zA, dinv, zB, emb, out, 0);
    k_spmv3<<<spmvBlocks, 256, 0, stream>>>(base, deg, csrc, zB, dinv, zA, emb, out, 1);
    k_spmv3<<<spmvBlocks, 256, 0, stream>>>(base, deg, csrc, zA, dinv, zB, emb, out, 2);
}